// Round 10
// baseline (342.428 us; speedup 1.0000x reference)
//
#include <hip/hip_runtime.h>
#include <math.h>

#define C 512
#define HW 4096
#define N 1024
#define NPIX 32768
#define MARGIN 2.0f

typedef short s16x8 __attribute__((ext_vector_type(8)));
typedef float f32x4 __attribute__((ext_vector_type(4)));

__device__ inline unsigned short f2bf(float f) {
    unsigned int u = __float_as_uint(f);
    return (unsigned short)((u + 0x7FFFu + ((u >> 16) & 1u)) >> 16);
}
__device__ inline float h2f(unsigned short u) {
    _Float16 h; __builtin_memcpy(&h, &u, 2); return (float)h;
}
__device__ inline unsigned short f2h(float f) {
    _Float16 h = (_Float16)f; unsigned short u; __builtin_memcpy(&u, &h, 2); return u;
}
__device__ inline unsigned int mono(float v) {
    unsigned int u = __float_as_uint(v);
    return (u & 0x80000000u) ? ~u : (u | 0x80000000u);
}
__device__ inline void gload_lds16(const void* gsrc, void* ldst) {
    __builtin_amdgcn_global_load_lds(
        (const __attribute__((address_space(1))) unsigned int*)gsrc,
        (__attribute__((address_space(3))) unsigned int*)ldst, 16, 0, 0);
}

// ---------- K0: row norms of centers (->cnorm) and clusters (->clnorm) ----------
__global__ __launch_bounds__(64) void k_norms(const float* __restrict__ centers,
                                              const float* __restrict__ clusters,
                                              float* __restrict__ cnorm,
                                              float* __restrict__ clnorm) {
    int r = blockIdx.x;
    const float* src = (r < N) ? (centers + (size_t)r * C) : (clusters + (size_t)(r - N) * C);
    int lane = threadIdx.x;
    float s = 0.f;
    for (int k = lane; k < C; k += 64) { float v = src[k]; s += v * v; }
    #pragma unroll
    for (int m = 1; m < 64; m <<= 1) s += __shfl_xor(s, m, 64);
    if (lane == 0) {
        float nrm = sqrtf(s);
        if (nrm < 1e-12f) nrm = 1e-12f;
        if (r < N) cnorm[r] = nrm; else clnorm[r - N] = nrm;
    }
}

// ---------- K1: M[i][j] = dot(centers[i],clusters[j]) / (cnorm[i]*clnorm[j]) ----------
__global__ __launch_bounds__(256) void k_gemmM(const float* __restrict__ centers,
                                               const float* __restrict__ clusters,
                                               const float* __restrict__ cnorm,
                                               const float* __restrict__ clnorm,
                                               float* __restrict__ M) {
    __shared__ float as[32][68];
    __shared__ float bs[32][68];
    int tid = threadIdx.x;
    int tx = tid & 15, ty = tid >> 4;
    int i0 = blockIdx.x * 64, j0 = blockIdx.y * 64;
    int lrow = tid >> 2, lkq = (tid & 3) * 8;
    float acc[4][4] = {};
    for (int kc = 0; kc < C; kc += 32) {
        float4 a0 = *(const float4*)(centers + (size_t)(i0 + lrow) * C + kc + lkq);
        float4 a1 = *(const float4*)(centers + (size_t)(i0 + lrow) * C + kc + lkq + 4);
        float4 b0 = *(const float4*)(clusters + (size_t)(j0 + lrow) * C + kc + lkq);
        float4 b1 = *(const float4*)(clusters + (size_t)(j0 + lrow) * C + kc + lkq + 4);
        __syncthreads();
        as[lkq+0][lrow]=a0.x; as[lkq+1][lrow]=a0.y; as[lkq+2][lrow]=a0.z; as[lkq+3][lrow]=a0.w;
        as[lkq+4][lrow]=a1.x; as[lkq+5][lrow]=a1.y; as[lkq+6][lrow]=a1.z; as[lkq+7][lrow]=a1.w;
        bs[lkq+0][lrow]=b0.x; bs[lkq+1][lrow]=b0.y; bs[lkq+2][lrow]=b0.z; bs[lkq+3][lrow]=b0.w;
        bs[lkq+4][lrow]=b1.x; bs[lkq+5][lrow]=b1.y; bs[lkq+6][lrow]=b1.z; bs[lkq+7][lrow]=b1.w;
        __syncthreads();
        #pragma unroll
        for (int k = 0; k < 32; k += 4) {
            float av[4][4], bv[4][4];
            #pragma unroll
            for (int kk = 0; kk < 4; ++kk) {
                float4 ta = *(const float4*)&as[k+kk][tx*4];
                float4 tb = *(const float4*)&bs[k+kk][ty*4];
                av[kk][0]=ta.x; av[kk][1]=ta.y; av[kk][2]=ta.z; av[kk][3]=ta.w;
                bv[kk][0]=tb.x; bv[kk][1]=tb.y; bv[kk][2]=tb.z; bv[kk][3]=tb.w;
            }
            #pragma unroll
            for (int kk = 0; kk < 4; ++kk)
                #pragma unroll
                for (int ii = 0; ii < 4; ++ii)
                    #pragma unroll
                    for (int jj = 0; jj < 4; ++jj)
                        acc[ii][jj] = fmaf(av[kk][ii], bv[kk][jj], acc[ii][jj]);
        }
    }
    float rci[4], rcj[4];
    #pragma unroll
    for (int ii = 0; ii < 4; ++ii) rci[ii] = cnorm[i0 + tx*4 + ii];
    #pragma unroll
    for (int jj = 0; jj < 4; ++jj) rcj[jj] = clnorm[j0 + ty*4 + jj];
    #pragma unroll
    for (int ii = 0; ii < 4; ++ii)
        #pragma unroll
        for (int jj = 0; jj < 4; ++jj)
            M[(size_t)(i0 + tx*4 + ii) * N + (j0 + ty*4 + jj)] = acc[ii][jj] / (rci[ii] * rcj[jj]);
}

// ---------- K2: per-row max + argmax (first-index tie-break) of M ----------
__global__ __launch_bounds__(256) void k_rowstat(const float* __restrict__ M,
                                                 float* __restrict__ rowmax,
                                                 int* __restrict__ rowarg) {
    __shared__ float sv[256];
    __shared__ int   sa[256];
    int i = blockIdx.x, tid = threadIdx.x;
    float bv = -INFINITY; int ba = 0;
    for (int j = tid; j < N; j += 256) {
        float v = M[(size_t)i * N + j];
        if (v > bv || (v == bv && j < ba)) { bv = v; ba = j; }
    }
    sv[tid] = bv; sa[tid] = ba;
    __syncthreads();
    for (int s = 128; s > 0; s >>= 1) {
        if (tid < s) {
            float v = sv[tid + s]; int a = sa[tid + s];
            if (v > sv[tid] || (v == sv[tid] && a < sa[tid])) { sv[tid] = v; sa[tid] = a; }
        }
        __syncthreads();
    }
    if (tid == 0) { rowmax[i] = sv[0]; rowarg[i] = sa[0]; }
}

// ---------- K3: transpose x[b][k][p] -> xT[b*4096+p][k] (fp32) ----------
__global__ __launch_bounds__(256) void k_prepT(const float* __restrict__ x,
                                               float* __restrict__ xT) {
    __shared__ float t[64][65];
    int bidx = blockIdx.x;              // 8 b * 8 ktile * 64 ptile
    int pt = bidx & 63, kt = (bidx >> 6) & 7, b = bidx >> 9;
    int r = threadIdx.x >> 4, c4 = (threadIdx.x & 15) * 4;
    const float* src = x + ((size_t)b * C + kt * 64) * HW + pt * 64;
    #pragma unroll
    for (int rr = 0; rr < 4; ++rr) {
        int row = rr * 16 + r;
        float4 v = *(const float4*)(src + (size_t)row * HW + c4);
        t[row][c4] = v.x; t[row][c4+1] = v.y; t[row][c4+2] = v.z; t[row][c4+3] = v.w;
    }
    __syncthreads();
    float* dst = xT + ((size_t)b * HW + pt * 64) * C + kt * 64;
    #pragma unroll
    for (int rr = 0; rr < 4; ++rr) {
        int row = rr * 16 + r;          // pixel within tile
        float4 v = { t[c4][row], t[c4+1][row], t[c4+2][row], t[c4+3][row] };
        *(float4*)(dst + (size_t)row * C + c4) = v;
    }
}

// ---------- K4: centers -> bf16 MFMA B-fragments; also zero pixbest ----------
__global__ __launch_bounds__(64) void k_cenfrag(const float* __restrict__ centers,
                                                unsigned short* __restrict__ cenB,
                                                unsigned long long* __restrict__ pixbest) {
    int f = blockIdx.x;                 // nt*16 + kt
    int lane = threadIdx.x;
    if (f < 512) pixbest[f * 64 + lane] = 0ull;   // 512*64 = 32768
    int nt = f >> 4, kt = f & 15;
    int r = lane & 15, g = lane >> 4;
    const float* src = centers + (size_t)(nt * 16 + r) * C + kt * 32 + g * 4;
    float4 lo = *(const float4*)src;
    float4 hi = *(const float4*)(src + 16);
    union { unsigned short us[8]; uint4 q; } u;
    u.us[0]=f2bf(lo.x); u.us[1]=f2bf(lo.y); u.us[2]=f2bf(lo.z); u.us[3]=f2bf(lo.w);
    u.us[4]=f2bf(hi.x); u.us[5]=f2bf(hi.y); u.us[6]=f2bf(hi.z); u.us[7]=f2bf(hi.w);
    *(uint4*)(cenB + ((size_t)f * 64 + lane) * 8) = u.q;
}

// ---------- K5: FUSED — 1024 blocks = 512 px-tiles x 2 n-halves; safe dbuf ----------
__global__ __launch_bounds__(256, 4) void k_fused(const float* __restrict__ xT,
                                                  const unsigned short* __restrict__ cenB,
                                                  const float* __restrict__ gumbel,
                                                  const float* __restrict__ centers,
                                                  unsigned long long* __restrict__ pixbest) {
    __shared__ unsigned short cen[2][8192];        // 2 x 16 KB cen tile dbuf
    __shared__ unsigned int candlist[4][256];
    __shared__ int candcount[4];

    int tid = threadIdx.x;
    int lane = tid & 63, w = tid >> 6;             // 4 waves; wave = px-tile
    int r = lane & 15, g = lane >> 4;

    int blk = blockIdx.x;
    int gr = blk & 1;                              // n-half: [gr*512, gr*512+512)
    int p0 = (blk >> 1) * 64;
    int b = p0 >> 12, hw0 = p0 & (HW - 1);

    if (tid < 4) candcount[tid] = 0;

    // ---- stage tile 0 of this half ----
    {
        const char* src = (const char*)cenB + (size_t)(gr * 32) * 16384 + w * 4096 + lane * 16;
        char* dst = (char*)&cen[0][0] + w * 4096;
        #pragma unroll
        for (int i = 0; i < 4; ++i) gload_lds16(src + i * 1024, dst + i * 1024);
    }

    // ---- A fragments: this wave's 16 px x 512 k bf16, straight from xT ----
    s16x8 a[16];
    {
        const float* xrow = xT + (size_t)(p0 + w * 16 + r) * C;
        #pragma unroll
        for (int kt = 0; kt < 16; ++kt) {
            float4 lo = *(const float4*)(xrow + kt * 32 + g * 4);
            float4 hi = *(const float4*)(xrow + kt * 32 + 16 + g * 4);
            s16x8 t;
            t[0]=(short)f2bf(lo.x); t[1]=(short)f2bf(lo.y); t[2]=(short)f2bf(lo.z); t[3]=(short)f2bf(lo.w);
            t[4]=(short)f2bf(hi.x); t[5]=(short)f2bf(hi.y); t[6]=(short)f2bf(hi.z); t[7]=(short)f2bf(hi.w);
            a[kt] = t;
        }
    }
    const float* gpx = gumbel + ((size_t)b * N + (size_t)gr * 512) * HW + hw0 + w * 16 + g * 4;
    float4 gv_c = *(const float4*)(gpx + (size_t)r * HW);   // t=0
    __syncthreads();                               // tile 0 staged, A-frags ready

    float m4[4] = {-INFINITY, -INFINITY, -INFINITY, -INFINITY};
    int cur = 0;

    for (int tc = 0; tc < 4; ++tc) {               // 4 chunks x 8 tiles = 32 n-tiles
        unsigned int keepH[16];
        #pragma unroll
        for (int s = 0; s < 8; ++s) {
            int t = tc * 8 + s;
            if (t < 31) {                          // issue next-tile staging early
                const char* src = (const char*)cenB + (size_t)(gr * 32 + t + 1) * 16384 + w * 4096 + lane * 16;
                char* dst = (char*)&cen[cur ^ 1][0] + w * 4096;
                #pragma unroll
                for (int i = 0; i < 4; ++i) gload_lds16(src + i * 1024, dst + i * 1024);
            }
            float4 gv_n = gv_c;
            if (t < 31) gv_n = *(const float4*)(gpx + (size_t)((t + 1) * 16 + r) * HW);
            const s16x8* bp = (const s16x8*)&cen[cur][0] + lane;
            f32x4 acc0 = {0.f,0.f,0.f,0.f}, acc1 = {0.f,0.f,0.f,0.f};
            #pragma unroll
            for (int kt = 0; kt < 16; kt += 2) {
                acc0 = __builtin_amdgcn_mfma_f32_16x16x32_bf16(a[kt],   bp[kt*64],     acc0, 0,0,0);
                acc1 = __builtin_amdgcn_mfma_f32_16x16x32_bf16(a[kt+1], bp[(kt+1)*64], acc1, 0,0,0);
            }
            float v0 = acc0[0]+acc1[0]+gv_c.x, v1 = acc0[1]+acc1[1]+gv_c.y;
            float v2 = acc0[2]+acc1[2]+gv_c.z, v3 = acc0[3]+acc1[3]+gv_c.w;
            m4[0]=fmaxf(m4[0],v0); m4[1]=fmaxf(m4[1],v1);
            m4[2]=fmaxf(m4[2],v2); m4[3]=fmaxf(m4[3],v3);
            keepH[s*2]   = (unsigned int)f2h(v0) | ((unsigned int)f2h(v1) << 16);
            keepH[s*2+1] = (unsigned int)f2h(v2) | ((unsigned int)f2h(v3) << 16);
            __syncthreads();                       // full drain: staging visible, reads consumed
            cur ^= 1;
            gv_c = gv_n;
        }
        // ---- chunk scan: per-pixel running max across r-lanes, candidate pushes ----
        #pragma unroll
        for (int s2 = 1; s2 < 16; s2 <<= 1) {
            #pragma unroll
            for (int j = 0; j < 4; ++j) m4[j] = fmaxf(m4[j], __shfl_xor(m4[j], s2, 64));
        }
        float thr[4];
        #pragma unroll
        for (int j = 0; j < 4; ++j) thr[j] = m4[j] - MARGIN;
        #pragma unroll
        for (int s = 0; s < 8; ++s) {
            int nn = ((gr * 32 + tc * 8 + s) << 4) + r;
            #pragma unroll
            for (int j2 = 0; j2 < 2; ++j2) {
                unsigned int pk = keepH[s * 2 + j2];
                float lo = h2f((unsigned short)(pk & 0xFFFFu));
                float hi = h2f((unsigned short)(pk >> 16));
                if (lo >= thr[j2 * 2]) {
                    int pos = atomicAdd(&candcount[w], 1);
                    if (pos < 256) candlist[w][pos] =
                        (unsigned int)nn | ((unsigned int)(w * 16 + g * 4 + j2 * 2) << 10);
                }
                if (hi >= thr[j2 * 2 + 1]) {
                    int pos = atomicAdd(&candcount[w], 1);
                    if (pos < 256) candlist[w][pos] =
                        (unsigned int)nn | ((unsigned int)(w * 16 + g * 4 + j2 * 2 + 1) << 10);
                }
            }
        }
    }

    // ---- exact fp32 refine: 4 candidates/wave in parallel, winner -> global atomicMax ----
    int cc = candcount[w]; if (cc > 256) cc = 256;
    int sl = lane & 15, cg = lane >> 4;
    for (int t0 = 0; t0 < cc; t0 += 4) {
        int c = t0 + cg;
        bool valid = c < cc;
        unsigned int e = candlist[w][valid ? c : 0];
        int n = (int)(e & 1023u), pl = (int)(e >> 10);
        const float* xr = xT + (size_t)(p0 + pl) * C;
        const float* cenr = centers + (size_t)n * C;
        float s = 0.f;
        #pragma unroll
        for (int m = 0; m < 8; ++m) {
            int G = sl + (m << 4);
            float4 xv = *(const float4*)(xr + (G << 2));
            float4 cv = *(const float4*)(cenr + (G << 2));
            s = fmaf(xv.x, cv.x, s); s = fmaf(xv.y, cv.y, s);
            s = fmaf(xv.z, cv.z, s); s = fmaf(xv.w, cv.w, s);
        }
        #pragma unroll
        for (int s2 = 1; s2 < 16; s2 <<= 1) s += __shfl_xor(s, s2, 64);
        if (valid && sl == 0) {
            float val = s + gumbel[((size_t)b * N + n) * HW + hw0 + pl];
            unsigned long long key = ((unsigned long long)mono(val) << 32) | (unsigned int)(1023 - n);
            atomicMax(&pixbest[p0 + pl], key);
        }
    }
}

// ---------- K6: idx decode, preds (as float) + per-block loss partial sums ----------
__global__ __launch_bounds__(256) void k_preds(const unsigned long long* __restrict__ pixbest,
                                               const float* __restrict__ rowmax,
                                               const int* __restrict__ rowarg,
                                               int* __restrict__ idxb,
                                               float* __restrict__ preds_out,
                                               float* __restrict__ partial) {
    __shared__ float sv[256];
    int gid = blockIdx.x * 256 + threadIdx.x;
    unsigned long long key = pixbest[gid];
    int i = 1023 - (int)(unsigned int)(key & 0xFFFFFFFFull);
    idxb[gid] = i;
    preds_out[gid] = (float)rowarg[i];
    sv[threadIdx.x] = rowmax[i];
    __syncthreads();
    for (int s = 128; s > 0; s >>= 1) {
        if (threadIdx.x < s) sv[threadIdx.x] += sv[threadIdx.x + s];
        __syncthreads();
    }
    if (threadIdx.x == 0) partial[blockIdx.x] = sv[0];
}

// ---------- K7: gather rows of src by idx and write transposed (coalesced) ----------
__global__ __launch_bounds__(256) void k_gather(const float* __restrict__ src, int ncols,
                                                const int* __restrict__ idx,
                                                float* __restrict__ dst) {
    __shared__ float rows[64][65];
    int tile = blockIdx.x;
    int col0 = blockIdx.y * 64;
    int tid = threadIdx.x;
    int lane = tid & 63, w = tid >> 6;
    int b = tile >> 6, hw0 = (tile & 63) << 6;
    #pragma unroll
    for (int r8 = 0; r8 < 16; ++r8) {
        int r = w * 16 + r8;
        int row = idx[tile * 64 + r];
        rows[r][lane] = src[(size_t)row * ncols + col0 + lane];
    }
    __syncthreads();
    #pragma unroll
    for (int jj = 0; jj < 16; ++jj) {
        int j = col0 + w * 16 + jj;
        dst[((size_t)b * ncols + j) * HW + hw0 + lane] = rows[lane][w * 16 + jj];
    }
}

// ---------- K8: finalize loss ----------
__global__ __launch_bounds__(128) void k_loss(const float* __restrict__ partial,
                                              float* __restrict__ out) {
    __shared__ float sv[128];
    sv[threadIdx.x] = partial[threadIdx.x];
    __syncthreads();
    for (int s = 64; s > 0; s >>= 1) {
        if (threadIdx.x < s) sv[threadIdx.x] += sv[threadIdx.x + s];
        __syncthreads();
    }
    if (threadIdx.x == 0) out[0] = -(sv[0] / 32768.0f);
}

extern "C" void kernel_launch(void* const* d_in, const int* in_sizes, int n_in,
                              void* d_out, int out_size, void* d_ws, size_t ws_size,
                              hipStream_t stream) {
    const float* x        = (const float*)d_in[0];
    const float* centers  = (const float*)d_in[1];
    const float* clusters = (const float*)d_in[2];
    const float* gumbel   = (const float*)d_in[3];
    float* out = (float*)d_out;

    char* w = (char*)d_ws;
    int*   idxb    = (int*)w;                                  // 128 KB
    float* cnorm   = (float*)(w + 131072);                     // 4 KB
    float* clnorm  = cnorm + 1024;
    float* rowmax  = clnorm + 1024;
    int*   rowarg  = (int*)(rowmax + 1024);
    float* partial = (float*)(rowarg + 1024);
    float* M       = (float*)(w + 262144);                     // 4 MB
    unsigned short* cenB = (unsigned short*)(w + 4456448);     // 1 MB
    unsigned long long* pixbest = (unsigned long long*)(w + 5505024); // 256 KB

    float* out_loss  = out;
    float* out_preds = out + 1;
    float* out_ip    = out + 1 + 32768;
    float* out_zq    = out + 1 + 32768 + (size_t)N * NPIX;

    // xT scratch lives in the zq output region (dead until the final gather)
    float* xT = out_zq;                                        // 32768 x 512 fp32, exact fit

    k_norms  <<<2048, 64, 0, stream>>>(centers, clusters, cnorm, clnorm);
    k_gemmM  <<<dim3(16, 16), 256, 0, stream>>>(centers, clusters, cnorm, clnorm, M);
    k_rowstat<<<1024, 256, 0, stream>>>(M, rowmax, rowarg);
    k_cenfrag<<<1024, 64, 0, stream>>>(centers, cenB, pixbest);
    k_prepT  <<<4096, 256, 0, stream>>>(x, xT);
    k_fused  <<<1024, 256, 0, stream>>>(xT, cenB, gumbel, centers, pixbest);
    k_preds  <<<128, 256, 0, stream>>>(pixbest, rowmax, rowarg, idxb, out_preds, partial);
    k_gather <<<dim3(512, 16), 256, 0, stream>>>(M, N, idxb, out_ip);
    k_gather <<<dim3(512, 8),  256, 0, stream>>>(centers, C, idxb, out_zq);
    k_loss   <<<1, 128, 0, stream>>>(partial, out_loss);
}

// Round 11
// 309.128 us; speedup vs baseline: 1.1077x; 1.1077x over previous
//
#include <hip/hip_runtime.h>
#include <math.h>

#define C 512
#define HW 4096
#define N 1024
#define NPIX 32768
#define MARGIN 2.0f

typedef short s16x8 __attribute__((ext_vector_type(8)));
typedef float f32x4 __attribute__((ext_vector_type(4)));

__device__ inline unsigned short f2bf(float f) {
    unsigned int u = __float_as_uint(f);
    return (unsigned short)((u + 0x7FFFu + ((u >> 16) & 1u)) >> 16);
}
__device__ inline float h2f(unsigned short u) {
    _Float16 h; __builtin_memcpy(&h, &u, 2); return (float)h;
}
__device__ inline unsigned short f2h(float f) {
    _Float16 h = (_Float16)f; unsigned short u; __builtin_memcpy(&u, &h, 2); return u;
}
__device__ inline unsigned int mono(float v) {
    unsigned int u = __float_as_uint(v);
    return (u & 0x80000000u) ? ~u : (u | 0x80000000u);
}
__device__ inline void gload_lds16(const void* gsrc, void* ldst) {
    __builtin_amdgcn_global_load_lds(
        (const __attribute__((address_space(1))) unsigned int*)gsrc,
        (__attribute__((address_space(3))) unsigned int*)ldst, 16, 0, 0);
}

// ---------- K0: row norms of centers (->cnorm) and clusters (->clnorm) ----------
__global__ __launch_bounds__(64) void k_norms(const float* __restrict__ centers,
                                              const float* __restrict__ clusters,
                                              float* __restrict__ cnorm,
                                              float* __restrict__ clnorm) {
    int r = blockIdx.x;
    const float* src = (r < N) ? (centers + (size_t)r * C) : (clusters + (size_t)(r - N) * C);
    int lane = threadIdx.x;
    float s = 0.f;
    for (int k = lane; k < C; k += 64) { float v = src[k]; s += v * v; }
    #pragma unroll
    for (int m = 1; m < 64; m <<= 1) s += __shfl_xor(s, m, 64);
    if (lane == 0) {
        float nrm = sqrtf(s);
        if (nrm < 1e-12f) nrm = 1e-12f;
        if (r < N) cnorm[r] = nrm; else clnorm[r - N] = nrm;
    }
}

// ---------- K1: M[i][j] = dot(centers[i],clusters[j]) / (cnorm[i]*clnorm[j]) ----------
__global__ __launch_bounds__(256) void k_gemmM(const float* __restrict__ centers,
                                               const float* __restrict__ clusters,
                                               const float* __restrict__ cnorm,
                                               const float* __restrict__ clnorm,
                                               float* __restrict__ M) {
    __shared__ float as[32][68];
    __shared__ float bs[32][68];
    int tid = threadIdx.x;
    int tx = tid & 15, ty = tid >> 4;
    int i0 = blockIdx.x * 64, j0 = blockIdx.y * 64;
    int lrow = tid >> 2, lkq = (tid & 3) * 8;
    float acc[4][4] = {};
    for (int kc = 0; kc < C; kc += 32) {
        float4 a0 = *(const float4*)(centers + (size_t)(i0 + lrow) * C + kc + lkq);
        float4 a1 = *(const float4*)(centers + (size_t)(i0 + lrow) * C + kc + lkq + 4);
        float4 b0 = *(const float4*)(clusters + (size_t)(j0 + lrow) * C + kc + lkq);
        float4 b1 = *(const float4*)(clusters + (size_t)(j0 + lrow) * C + kc + lkq + 4);
        __syncthreads();
        as[lkq+0][lrow]=a0.x; as[lkq+1][lrow]=a0.y; as[lkq+2][lrow]=a0.z; as[lkq+3][lrow]=a0.w;
        as[lkq+4][lrow]=a1.x; as[lkq+5][lrow]=a1.y; as[lkq+6][lrow]=a1.z; as[lkq+7][lrow]=a1.w;
        bs[lkq+0][lrow]=b0.x; bs[lkq+1][lrow]=b0.y; bs[lkq+2][lrow]=b0.z; bs[lkq+3][lrow]=b0.w;
        bs[lkq+4][lrow]=b1.x; bs[lkq+5][lrow]=b1.y; bs[lkq+6][lrow]=b1.z; bs[lkq+7][lrow]=b1.w;
        __syncthreads();
        #pragma unroll
        for (int k = 0; k < 32; k += 4) {
            float av[4][4], bv[4][4];
            #pragma unroll
            for (int kk = 0; kk < 4; ++kk) {
                float4 ta = *(const float4*)&as[k+kk][tx*4];
                float4 tb = *(const float4*)&bs[k+kk][ty*4];
                av[kk][0]=ta.x; av[kk][1]=ta.y; av[kk][2]=ta.z; av[kk][3]=ta.w;
                bv[kk][0]=tb.x; bv[kk][1]=tb.y; bv[kk][2]=tb.z; bv[kk][3]=tb.w;
            }
            #pragma unroll
            for (int kk = 0; kk < 4; ++kk)
                #pragma unroll
                for (int ii = 0; ii < 4; ++ii)
                    #pragma unroll
                    for (int jj = 0; jj < 4; ++jj)
                        acc[ii][jj] = fmaf(av[kk][ii], bv[kk][jj], acc[ii][jj]);
        }
    }
    float rci[4], rcj[4];
    #pragma unroll
    for (int ii = 0; ii < 4; ++ii) rci[ii] = cnorm[i0 + tx*4 + ii];
    #pragma unroll
    for (int jj = 0; jj < 4; ++jj) rcj[jj] = clnorm[j0 + ty*4 + jj];
    #pragma unroll
    for (int ii = 0; ii < 4; ++ii)
        #pragma unroll
        for (int jj = 0; jj < 4; ++jj)
            M[(size_t)(i0 + tx*4 + ii) * N + (j0 + ty*4 + jj)] = acc[ii][jj] / (rci[ii] * rcj[jj]);
}

// ---------- K2: per-row max + argmax (first-index tie-break) of M ----------
__global__ __launch_bounds__(256) void k_rowstat(const float* __restrict__ M,
                                                 float* __restrict__ rowmax,
                                                 int* __restrict__ rowarg) {
    __shared__ float sv[256];
    __shared__ int   sa[256];
    int i = blockIdx.x, tid = threadIdx.x;
    float bv = -INFINITY; int ba = 0;
    for (int j = tid; j < N; j += 256) {
        float v = M[(size_t)i * N + j];
        if (v > bv || (v == bv && j < ba)) { bv = v; ba = j; }
    }
    sv[tid] = bv; sa[tid] = ba;
    __syncthreads();
    for (int s = 128; s > 0; s >>= 1) {
        if (tid < s) {
            float v = sv[tid + s]; int a = sa[tid + s];
            if (v > sv[tid] || (v == sv[tid] && a < sa[tid])) { sv[tid] = v; sa[tid] = a; }
        }
        __syncthreads();
    }
    if (tid == 0) { rowmax[i] = sv[0]; rowarg[i] = sa[0]; }
}

// ---------- K3: transpose x[b][k][p] -> xT[b*4096+p][k] (fp32) ----------
__global__ __launch_bounds__(256) void k_prepT(const float* __restrict__ x,
                                               float* __restrict__ xT) {
    __shared__ float t[64][65];
    int bidx = blockIdx.x;              // 8 b * 8 ktile * 64 ptile
    int pt = bidx & 63, kt = (bidx >> 6) & 7, b = bidx >> 9;
    int r = threadIdx.x >> 4, c4 = (threadIdx.x & 15) * 4;
    const float* src = x + ((size_t)b * C + kt * 64) * HW + pt * 64;
    #pragma unroll
    for (int rr = 0; rr < 4; ++rr) {
        int row = rr * 16 + r;
        float4 v = *(const float4*)(src + (size_t)row * HW + c4);
        t[row][c4] = v.x; t[row][c4+1] = v.y; t[row][c4+2] = v.z; t[row][c4+3] = v.w;
    }
    __syncthreads();
    float* dst = xT + ((size_t)b * HW + pt * 64) * C + kt * 64;
    #pragma unroll
    for (int rr = 0; rr < 4; ++rr) {
        int row = rr * 16 + r;          // pixel within tile
        float4 v = { t[c4][row], t[c4+1][row], t[c4+2][row], t[c4+3][row] };
        *(float4*)(dst + (size_t)row * C + c4) = v;
    }
}

// ---------- K4: centers -> bf16 MFMA B-fragments; also zero pixbest ----------
__global__ __launch_bounds__(64) void k_cenfrag(const float* __restrict__ centers,
                                                unsigned short* __restrict__ cenB,
                                                unsigned long long* __restrict__ pixbest) {
    int f = blockIdx.x;                 // nt*16 + kt
    int lane = threadIdx.x;
    if (f < 512) pixbest[f * 64 + lane] = 0ull;   // 512*64 = 32768
    int nt = f >> 4, kt = f & 15;
    int r = lane & 15, g = lane >> 4;
    const float* src = centers + (size_t)(nt * 16 + r) * C + kt * 32 + g * 4;
    float4 lo = *(const float4*)src;
    float4 hi = *(const float4*)(src + 16);
    union { unsigned short us[8]; uint4 q; } u;
    u.us[0]=f2bf(lo.x); u.us[1]=f2bf(lo.y); u.us[2]=f2bf(lo.z); u.us[3]=f2bf(lo.w);
    u.us[4]=f2bf(hi.x); u.us[5]=f2bf(hi.y); u.us[6]=f2bf(hi.z); u.us[7]=f2bf(hi.w);
    *(uint4*)(cenB + ((size_t)f * 64 + lane) * 8) = u.q;
}

// ---------- K5: FUSED — 1024 blocks = 512 px-tiles x 2 n-halves; safe dbuf ----------
__global__ __launch_bounds__(256, 3) void k_fused(const float* __restrict__ xT,
                                                  const unsigned short* __restrict__ cenB,
                                                  const float* __restrict__ gumbel,
                                                  const float* __restrict__ centers,
                                                  unsigned long long* __restrict__ pixbest) {
    __shared__ unsigned short cen[2][8192];        // 2 x 16 KB cen tile dbuf
    __shared__ unsigned int candlist[4][256];
    __shared__ int candcount[4];

    int tid = threadIdx.x;
    int lane = tid & 63, w = tid >> 6;             // 4 waves; wave = px-tile
    int r = lane & 15, g = lane >> 4;

    int blk = blockIdx.x;
    int gr = blk & 1;                              // n-half: [gr*512, gr*512+512)
    int p0 = (blk >> 1) * 64;
    int b = p0 >> 12, hw0 = p0 & (HW - 1);

    if (tid < 4) candcount[tid] = 0;

    // ---- stage tile 0 of this half ----
    {
        const char* src = (const char*)cenB + (size_t)(gr * 32) * 16384 + w * 4096 + lane * 16;
        char* dst = (char*)&cen[0][0] + w * 4096;
        #pragma unroll
        for (int i = 0; i < 4; ++i) gload_lds16(src + i * 1024, dst + i * 1024);
    }

    // ---- A fragments: this wave's 16 px x 512 k bf16, straight from xT ----
    s16x8 a[16];
    {
        const float* xrow = xT + (size_t)(p0 + w * 16 + r) * C;
        #pragma unroll
        for (int kt = 0; kt < 16; ++kt) {
            float4 lo = *(const float4*)(xrow + kt * 32 + g * 4);
            float4 hi = *(const float4*)(xrow + kt * 32 + 16 + g * 4);
            s16x8 t;
            t[0]=(short)f2bf(lo.x); t[1]=(short)f2bf(lo.y); t[2]=(short)f2bf(lo.z); t[3]=(short)f2bf(lo.w);
            t[4]=(short)f2bf(hi.x); t[5]=(short)f2bf(hi.y); t[6]=(short)f2bf(hi.z); t[7]=(short)f2bf(hi.w);
            a[kt] = t;
        }
    }
    const float* gpx = gumbel + ((size_t)b * N + (size_t)gr * 512) * HW + hw0 + w * 16 + g * 4;
    float4 gv_c = *(const float4*)(gpx + (size_t)r * HW);   // t=0
    __syncthreads();                               // tile 0 staged, A-frags ready

    float m4[4] = {-INFINITY, -INFINITY, -INFINITY, -INFINITY};
    int cur = 0;

    for (int tc = 0; tc < 4; ++tc) {               // 4 chunks x 8 tiles = 32 n-tiles
        unsigned int keepH[16];
        #pragma unroll
        for (int s = 0; s < 8; ++s) {
            int t = tc * 8 + s;
            if (t < 31) {                          // issue next-tile staging early
                const char* src = (const char*)cenB + (size_t)(gr * 32 + t + 1) * 16384 + w * 4096 + lane * 16;
                char* dst = (char*)&cen[cur ^ 1][0] + w * 4096;
                #pragma unroll
                for (int i = 0; i < 4; ++i) gload_lds16(src + i * 1024, dst + i * 1024);
            }
            float4 gv_n = gv_c;
            if (t < 31) gv_n = *(const float4*)(gpx + (size_t)((t + 1) * 16 + r) * HW);
            const s16x8* bp = (const s16x8*)&cen[cur][0] + lane;
            f32x4 acc0 = {0.f,0.f,0.f,0.f}, acc1 = {0.f,0.f,0.f,0.f};
            #pragma unroll
            for (int kt = 0; kt < 16; kt += 2) {
                acc0 = __builtin_amdgcn_mfma_f32_16x16x32_bf16(a[kt],   bp[kt*64],     acc0, 0,0,0);
                acc1 = __builtin_amdgcn_mfma_f32_16x16x32_bf16(a[kt+1], bp[(kt+1)*64], acc1, 0,0,0);
            }
            float v0 = acc0[0]+acc1[0]+gv_c.x, v1 = acc0[1]+acc1[1]+gv_c.y;
            float v2 = acc0[2]+acc1[2]+gv_c.z, v3 = acc0[3]+acc1[3]+gv_c.w;
            m4[0]=fmaxf(m4[0],v0); m4[1]=fmaxf(m4[1],v1);
            m4[2]=fmaxf(m4[2],v2); m4[3]=fmaxf(m4[3],v3);
            keepH[s*2]   = (unsigned int)f2h(v0) | ((unsigned int)f2h(v1) << 16);
            keepH[s*2+1] = (unsigned int)f2h(v2) | ((unsigned int)f2h(v3) << 16);
            __syncthreads();                       // full drain: staging visible, reads consumed
            cur ^= 1;
            gv_c = gv_n;
        }
        // ---- chunk scan: per-pixel running max across r-lanes, candidate pushes ----
        #pragma unroll
        for (int s2 = 1; s2 < 16; s2 <<= 1) {
            #pragma unroll
            for (int j = 0; j < 4; ++j) m4[j] = fmaxf(m4[j], __shfl_xor(m4[j], s2, 64));
        }
        float thr[4];
        #pragma unroll
        for (int j = 0; j < 4; ++j) thr[j] = m4[j] - MARGIN;
        #pragma unroll
        for (int s = 0; s < 8; ++s) {
            int nn = ((gr * 32 + tc * 8 + s) << 4) + r;
            #pragma unroll
            for (int j2 = 0; j2 < 2; ++j2) {
                unsigned int pk = keepH[s * 2 + j2];
                float lo = h2f((unsigned short)(pk & 0xFFFFu));
                float hi = h2f((unsigned short)(pk >> 16));
                if (lo >= thr[j2 * 2]) {
                    int pos = atomicAdd(&candcount[w], 1);
                    if (pos < 256) candlist[w][pos] =
                        (unsigned int)nn | ((unsigned int)(w * 16 + g * 4 + j2 * 2) << 10);
                }
                if (hi >= thr[j2 * 2 + 1]) {
                    int pos = atomicAdd(&candcount[w], 1);
                    if (pos < 256) candlist[w][pos] =
                        (unsigned int)nn | ((unsigned int)(w * 16 + g * 4 + j2 * 2 + 1) << 10);
                }
            }
        }
    }

    // ---- exact fp32 refine: 4 candidates/wave in parallel, winner -> global atomicMax ----
    int cc = candcount[w]; if (cc > 256) cc = 256;
    int sl = lane & 15, cg = lane >> 4;
    for (int t0 = 0; t0 < cc; t0 += 4) {
        int c = t0 + cg;
        bool valid = c < cc;
        unsigned int e = candlist[w][valid ? c : 0];
        int n = (int)(e & 1023u), pl = (int)(e >> 10);
        const float* xr = xT + (size_t)(p0 + pl) * C;
        const float* cenr = centers + (size_t)n * C;
        float s = 0.f;
        #pragma unroll
        for (int m = 0; m < 8; ++m) {
            int G = sl + (m << 4);
            float4 xv = *(const float4*)(xr + (G << 2));
            float4 cv = *(const float4*)(cenr + (G << 2));
            s = fmaf(xv.x, cv.x, s); s = fmaf(xv.y, cv.y, s);
            s = fmaf(xv.z, cv.z, s); s = fmaf(xv.w, cv.w, s);
        }
        #pragma unroll
        for (int s2 = 1; s2 < 16; s2 <<= 1) s += __shfl_xor(s, s2, 64);
        if (valid && sl == 0) {
            float val = s + gumbel[((size_t)b * N + n) * HW + hw0 + pl];
            unsigned long long key = ((unsigned long long)mono(val) << 32) | (unsigned int)(1023 - n);
            atomicMax(&pixbest[p0 + pl], key);
        }
    }
}

// ---------- K6: idx decode, preds (as float) + per-block loss partial sums ----------
__global__ __launch_bounds__(256) void k_preds(const unsigned long long* __restrict__ pixbest,
                                               const float* __restrict__ rowmax,
                                               const int* __restrict__ rowarg,
                                               int* __restrict__ idxb,
                                               float* __restrict__ preds_out,
                                               float* __restrict__ partial) {
    __shared__ float sv[256];
    int gid = blockIdx.x * 256 + threadIdx.x;
    unsigned long long key = pixbest[gid];
    int i = 1023 - (int)(unsigned int)(key & 0xFFFFFFFFull);
    idxb[gid] = i;
    preds_out[gid] = (float)rowarg[i];
    sv[threadIdx.x] = rowmax[i];
    __syncthreads();
    for (int s = 128; s > 0; s >>= 1) {
        if (threadIdx.x < s) sv[threadIdx.x] += sv[threadIdx.x + s];
        __syncthreads();
    }
    if (threadIdx.x == 0) partial[blockIdx.x] = sv[0];
}

// ---------- K7: gather rows of src by idx and write transposed (coalesced) ----------
__global__ __launch_bounds__(256) void k_gather(const float* __restrict__ src, int ncols,
                                                const int* __restrict__ idx,
                                                float* __restrict__ dst) {
    __shared__ float rows[64][65];
    int tile = blockIdx.x;
    int col0 = blockIdx.y * 64;
    int tid = threadIdx.x;
    int lane = tid & 63, w = tid >> 6;
    int b = tile >> 6, hw0 = (tile & 63) << 6;
    #pragma unroll
    for (int r8 = 0; r8 < 16; ++r8) {
        int r = w * 16 + r8;
        int row = idx[tile * 64 + r];
        rows[r][lane] = src[(size_t)row * ncols + col0 + lane];
    }
    __syncthreads();
    #pragma unroll
    for (int jj = 0; jj < 16; ++jj) {
        int j = col0 + w * 16 + jj;
        dst[((size_t)b * ncols + j) * HW + hw0 + lane] = rows[lane][w * 16 + jj];
    }
}

// ---------- K8: finalize loss ----------
__global__ __launch_bounds__(128) void k_loss(const float* __restrict__ partial,
                                              float* __restrict__ out) {
    __shared__ float sv[128];
    sv[threadIdx.x] = partial[threadIdx.x];
    __syncthreads();
    for (int s = 64; s > 0; s >>= 1) {
        if (threadIdx.x < s) sv[threadIdx.x] += sv[threadIdx.x + s];
        __syncthreads();
    }
    if (threadIdx.x == 0) out[0] = -(sv[0] / 32768.0f);
}

extern "C" void kernel_launch(void* const* d_in, const int* in_sizes, int n_in,
                              void* d_out, int out_size, void* d_ws, size_t ws_size,
                              hipStream_t stream) {
    const float* x        = (const float*)d_in[0];
    const float* centers  = (const float*)d_in[1];
    const float* clusters = (const float*)d_in[2];
    const float* gumbel   = (const float*)d_in[3];
    float* out = (float*)d_out;

    char* w = (char*)d_ws;
    int*   idxb    = (int*)w;                                  // 128 KB
    float* cnorm   = (float*)(w + 131072);                     // 4 KB
    float* clnorm  = cnorm + 1024;
    float* rowmax  = clnorm + 1024;
    int*   rowarg  = (int*)(rowmax + 1024);
    float* partial = (float*)(rowarg + 1024);
    float* M       = (float*)(w + 262144);                     // 4 MB
    unsigned short* cenB = (unsigned short*)(w + 4456448);     // 1 MB
    unsigned long long* pixbest = (unsigned long long*)(w + 5505024); // 256 KB

    float* out_loss  = out;
    float* out_preds = out + 1;
    float* out_ip    = out + 1 + 32768;
    float* out_zq    = out + 1 + 32768 + (size_t)N * NPIX;

    // xT scratch lives in the zq output region (dead until the final gather)
    float* xT = out_zq;                                        // 32768 x 512 fp32, exact fit

    k_norms  <<<2048, 64, 0, stream>>>(centers, clusters, cnorm, clnorm);
    k_gemmM  <<<dim3(16, 16), 256, 0, stream>>>(centers, clusters, cnorm, clnorm, M);
    k_rowstat<<<1024, 256, 0, stream>>>(M, rowmax, rowarg);
    k_cenfrag<<<1024, 64, 0, stream>>>(centers, cenB, pixbest);
    k_prepT  <<<4096, 256, 0, stream>>>(x, xT);
    k_fused  <<<1024, 256, 0, stream>>>(xT, cenB, gumbel, centers, pixbest);
    k_preds  <<<128, 256, 0, stream>>>(pixbest, rowmax, rowarg, idxb, out_preds, partial);
    k_gather <<<dim3(512, 16), 256, 0, stream>>>(M, N, idxb, out_ip);
    k_gather <<<dim3(512, 8),  256, 0, stream>>>(centers, C, idxb, out_zq);
    k_loss   <<<1, 128, 0, stream>>>(partial, out_loss);
}

// Round 12
// 298.356 us; speedup vs baseline: 1.1477x; 1.0361x over previous
//
#include <hip/hip_runtime.h>
#include <math.h>

#define C 512
#define HW 4096
#define N 1024
#define NPIX 32768
#define MARGIN 2.0f

typedef short s16x8 __attribute__((ext_vector_type(8)));
typedef float f32x4 __attribute__((ext_vector_type(4)));

__device__ inline unsigned short f2bf(float f) {
    unsigned int u = __float_as_uint(f);
    return (unsigned short)((u + 0x7FFFu + ((u >> 16) & 1u)) >> 16);
}
__device__ inline float h2f(unsigned short u) {
    _Float16 h; __builtin_memcpy(&h, &u, 2); return (float)h;
}
__device__ inline unsigned short f2h(float f) {
    _Float16 h = (_Float16)f; unsigned short u; __builtin_memcpy(&u, &h, 2); return u;
}
__device__ inline unsigned int mono(float v) {
    unsigned int u = __float_as_uint(v);
    return (u & 0x80000000u) ? ~u : (u | 0x80000000u);
}
__device__ inline void gload_lds16(const void* gsrc, void* ldst) {
    __builtin_amdgcn_global_load_lds(
        (const __attribute__((address_space(1))) unsigned int*)gsrc,
        (__attribute__((address_space(3))) unsigned int*)ldst, 16, 0, 0);
}

// ---------- K0: row norms of centers (->cnorm) and clusters (->clnorm) ----------
__global__ __launch_bounds__(64) void k_norms(const float* __restrict__ centers,
                                              const float* __restrict__ clusters,
                                              float* __restrict__ cnorm,
                                              float* __restrict__ clnorm) {
    int r = blockIdx.x;
    const float* src = (r < N) ? (centers + (size_t)r * C) : (clusters + (size_t)(r - N) * C);
    int lane = threadIdx.x;
    float s = 0.f;
    for (int k = lane; k < C; k += 64) { float v = src[k]; s += v * v; }
    #pragma unroll
    for (int m = 1; m < 64; m <<= 1) s += __shfl_xor(s, m, 64);
    if (lane == 0) {
        float nrm = sqrtf(s);
        if (nrm < 1e-12f) nrm = 1e-12f;
        if (r < N) cnorm[r] = nrm; else clnorm[r - N] = nrm;
    }
}

// ---------- K1: M[i][j] = dot(centers[i],clusters[j]) / (cnorm[i]*clnorm[j]) ----------
__global__ __launch_bounds__(256) void k_gemmM(const float* __restrict__ centers,
                                               const float* __restrict__ clusters,
                                               const float* __restrict__ cnorm,
                                               const float* __restrict__ clnorm,
                                               float* __restrict__ M) {
    __shared__ float as[32][68];
    __shared__ float bs[32][68];
    int tid = threadIdx.x;
    int tx = tid & 15, ty = tid >> 4;
    int i0 = blockIdx.x * 64, j0 = blockIdx.y * 64;
    int lrow = tid >> 2, lkq = (tid & 3) * 8;
    float acc[4][4] = {};
    for (int kc = 0; kc < C; kc += 32) {
        float4 a0 = *(const float4*)(centers + (size_t)(i0 + lrow) * C + kc + lkq);
        float4 a1 = *(const float4*)(centers + (size_t)(i0 + lrow) * C + kc + lkq + 4);
        float4 b0 = *(const float4*)(clusters + (size_t)(j0 + lrow) * C + kc + lkq);
        float4 b1 = *(const float4*)(clusters + (size_t)(j0 + lrow) * C + kc + lkq + 4);
        __syncthreads();
        as[lkq+0][lrow]=a0.x; as[lkq+1][lrow]=a0.y; as[lkq+2][lrow]=a0.z; as[lkq+3][lrow]=a0.w;
        as[lkq+4][lrow]=a1.x; as[lkq+5][lrow]=a1.y; as[lkq+6][lrow]=a1.z; as[lkq+7][lrow]=a1.w;
        bs[lkq+0][lrow]=b0.x; bs[lkq+1][lrow]=b0.y; bs[lkq+2][lrow]=b0.z; bs[lkq+3][lrow]=b0.w;
        bs[lkq+4][lrow]=b1.x; bs[lkq+5][lrow]=b1.y; bs[lkq+6][lrow]=b1.z; bs[lkq+7][lrow]=b1.w;
        __syncthreads();
        #pragma unroll
        for (int k = 0; k < 32; k += 4) {
            float av[4][4], bv[4][4];
            #pragma unroll
            for (int kk = 0; kk < 4; ++kk) {
                float4 ta = *(const float4*)&as[k+kk][tx*4];
                float4 tb = *(const float4*)&bs[k+kk][ty*4];
                av[kk][0]=ta.x; av[kk][1]=ta.y; av[kk][2]=ta.z; av[kk][3]=ta.w;
                bv[kk][0]=tb.x; bv[kk][1]=tb.y; bv[kk][2]=tb.z; bv[kk][3]=tb.w;
            }
            #pragma unroll
            for (int kk = 0; kk < 4; ++kk)
                #pragma unroll
                for (int ii = 0; ii < 4; ++ii)
                    #pragma unroll
                    for (int jj = 0; jj < 4; ++jj)
                        acc[ii][jj] = fmaf(av[kk][ii], bv[kk][jj], acc[ii][jj]);
        }
    }
    float rci[4], rcj[4];
    #pragma unroll
    for (int ii = 0; ii < 4; ++ii) rci[ii] = cnorm[i0 + tx*4 + ii];
    #pragma unroll
    for (int jj = 0; jj < 4; ++jj) rcj[jj] = clnorm[j0 + ty*4 + jj];
    #pragma unroll
    for (int ii = 0; ii < 4; ++ii)
        #pragma unroll
        for (int jj = 0; jj < 4; ++jj)
            M[(size_t)(i0 + tx*4 + ii) * N + (j0 + ty*4 + jj)] = acc[ii][jj] / (rci[ii] * rcj[jj]);
}

// ---------- K2: per-row max + argmax (first-index tie-break) of M ----------
__global__ __launch_bounds__(256) void k_rowstat(const float* __restrict__ M,
                                                 float* __restrict__ rowmax,
                                                 int* __restrict__ rowarg) {
    __shared__ float sv[256];
    __shared__ int   sa[256];
    int i = blockIdx.x, tid = threadIdx.x;
    float bv = -INFINITY; int ba = 0;
    for (int j = tid; j < N; j += 256) {
        float v = M[(size_t)i * N + j];
        if (v > bv || (v == bv && j < ba)) { bv = v; ba = j; }
    }
    sv[tid] = bv; sa[tid] = ba;
    __syncthreads();
    for (int s = 128; s > 0; s >>= 1) {
        if (tid < s) {
            float v = sv[tid + s]; int a = sa[tid + s];
            if (v > sv[tid] || (v == sv[tid] && a < sa[tid])) { sv[tid] = v; sa[tid] = a; }
        }
        __syncthreads();
    }
    if (tid == 0) { rowmax[i] = sv[0]; rowarg[i] = sa[0]; }
}

// ---------- K3: transpose x[b][k][p] -> xT[b*4096+p][k] (fp32) ----------
__global__ __launch_bounds__(256) void k_prepT(const float* __restrict__ x,
                                               float* __restrict__ xT) {
    __shared__ float t[64][65];
    int bidx = blockIdx.x;              // 8 b * 8 ktile * 64 ptile
    int pt = bidx & 63, kt = (bidx >> 6) & 7, b = bidx >> 9;
    int r = threadIdx.x >> 4, c4 = (threadIdx.x & 15) * 4;
    const float* src = x + ((size_t)b * C + kt * 64) * HW + pt * 64;
    #pragma unroll
    for (int rr = 0; rr < 4; ++rr) {
        int row = rr * 16 + r;
        float4 v = *(const float4*)(src + (size_t)row * HW + c4);
        t[row][c4] = v.x; t[row][c4+1] = v.y; t[row][c4+2] = v.z; t[row][c4+3] = v.w;
    }
    __syncthreads();
    float* dst = xT + ((size_t)b * HW + pt * 64) * C + kt * 64;
    #pragma unroll
    for (int rr = 0; rr < 4; ++rr) {
        int row = rr * 16 + r;          // pixel within tile
        float4 v = { t[c4][row], t[c4+1][row], t[c4+2][row], t[c4+3][row] };
        *(float4*)(dst + (size_t)row * C + c4) = v;
    }
}

// ---------- K4: centers -> bf16 MFMA B-fragments (fragment-linear) ----------
__global__ __launch_bounds__(64) void k_cenfrag(const float* __restrict__ centers,
                                                unsigned short* __restrict__ cenB) {
    int f = blockIdx.x;                 // nt*16 + kt
    int nt = f >> 4, kt = f & 15;
    int lane = threadIdx.x;
    int r = lane & 15, g = lane >> 4;
    const float* src = centers + (size_t)(nt * 16 + r) * C + kt * 32 + g * 4;
    float4 lo = *(const float4*)src;
    float4 hi = *(const float4*)(src + 16);
    union { unsigned short us[8]; uint4 q; } u;
    u.us[0]=f2bf(lo.x); u.us[1]=f2bf(lo.y); u.us[2]=f2bf(lo.z); u.us[3]=f2bf(lo.w);
    u.us[4]=f2bf(hi.x); u.us[5]=f2bf(hi.y); u.us[6]=f2bf(hi.z); u.us[7]=f2bf(hi.w);
    *(uint4*)(cenB + ((size_t)f * 64 + lane) * 8) = u.q;
}

// ---------- K5: FUSED — 512 blocks x 64 px, full n-sweep, async cen+gumbel LDS dbuf ----------
__global__ __launch_bounds__(256, 3) void k_fused(const float* __restrict__ xT,
                                                  const unsigned short* __restrict__ cenB,
                                                  const float* __restrict__ gumbel,
                                                  const float* __restrict__ centers,
                                                  int* __restrict__ idxb) {
    __shared__ unsigned short cen[2][8192];        // 2 x 16 KB cen tile dbuf
    __shared__ float glds[2][1024];                // 2 x 4 KB gumbel tile dbuf (16n x 64px, XOR-swz)
    __shared__ unsigned long long pixkey[64];
    __shared__ unsigned int candlist[4][256];
    __shared__ int candcount[4];

    int tid = threadIdx.x;
    int lane = tid & 63, w = tid >> 6;             // 4 waves; wave = px-tile
    int r = lane & 15, g = lane >> 4;

    int p0 = blockIdx.x * 64;
    int b = p0 >> 12, hw0 = p0 & (HW - 1);

    if (tid < 64) pixkey[tid] = 0ull;
    if (tid < 4) candcount[tid] = 0;

    // gumbel staging helper indices: thread tid stages row=tid>>4, granule m=tid&15.
    // Source is pre-swizzled (m173): granule m of row holds px-granule (m ^ row).
    int grow_ = tid >> 4;
    int gcol_ = ((tid ^ (tid >> 4)) & 15) * 4;     // px offset (floats)
    const float* gbase = gumbel + (size_t)b * N * HW + hw0 + gcol_;

    // ---- stage tile 0: cen + gumbel ----
    {
        const char* src = (const char*)cenB + w * 4096 + lane * 16;
        char* dst = (char*)&cen[0][0] + w * 4096;
        #pragma unroll
        for (int i = 0; i < 4; ++i) gload_lds16(src + i * 1024, dst + i * 1024);
        gload_lds16(gbase + (size_t)grow_ * HW, (char*)&glds[0][0] + tid * 16);
    }

    // ---- A fragments: this wave's 16 px x 512 k bf16, straight from xT ----
    s16x8 a[16];
    {
        const float* xrow = xT + (size_t)(p0 + w * 16 + r) * C;
        #pragma unroll
        for (int kt = 0; kt < 16; ++kt) {
            float4 lo = *(const float4*)(xrow + kt * 32 + g * 4);
            float4 hi = *(const float4*)(xrow + kt * 32 + 16 + g * 4);
            s16x8 t;
            t[0]=(short)f2bf(lo.x); t[1]=(short)f2bf(lo.y); t[2]=(short)f2bf(lo.z); t[3]=(short)f2bf(lo.w);
            t[4]=(short)f2bf(hi.x); t[5]=(short)f2bf(hi.y); t[6]=(short)f2bf(hi.z); t[7]=(short)f2bf(hi.w);
            a[kt] = t;
        }
    }
    __syncthreads();                               // tile 0 staged, A-frags ready

    float m4[4] = {-INFINITY, -INFINITY, -INFINITY, -INFINITY};
    int cur = 0;
    int gswz = r * 64 + ((((w << 2) + g) ^ r) << 2);   // float idx of this lane's gumbel quad

    for (int tc = 0; tc < 8; ++tc) {               // 8 chunks x 8 tiles = 64 n-tiles
        unsigned int keepH[16];
        #pragma unroll
        for (int s = 0; s < 8; ++s) {
            int t = tc * 8 + s;
            if (t < 63) {                          // issue next-tile staging early
                const char* src = (const char*)cenB + (size_t)(t + 1) * 16384 + w * 4096 + lane * 16;
                char* dst = (char*)&cen[cur ^ 1][0] + w * 4096;
                #pragma unroll
                for (int i = 0; i < 4; ++i) gload_lds16(src + i * 1024, dst + i * 1024);
                gload_lds16(gbase + (size_t)((t + 1) * 16 + grow_) * HW,
                            (char*)&glds[cur ^ 1][0] + tid * 16);
            }
            const s16x8* bp = (const s16x8*)&cen[cur][0] + lane;
            f32x4 acc0 = {0.f,0.f,0.f,0.f}, acc1 = {0.f,0.f,0.f,0.f};
            #pragma unroll
            for (int kt = 0; kt < 16; kt += 2) {
                acc0 = __builtin_amdgcn_mfma_f32_16x16x32_bf16(a[kt],   bp[kt*64],     acc0, 0,0,0);
                acc1 = __builtin_amdgcn_mfma_f32_16x16x32_bf16(a[kt+1], bp[(kt+1)*64], acc1, 0,0,0);
            }
            f32x4 gv = *(const f32x4*)&glds[cur][gswz];
            float v0 = acc0[0]+acc1[0]+gv[0], v1 = acc0[1]+acc1[1]+gv[1];
            float v2 = acc0[2]+acc1[2]+gv[2], v3 = acc0[3]+acc1[3]+gv[3];
            m4[0]=fmaxf(m4[0],v0); m4[1]=fmaxf(m4[1],v1);
            m4[2]=fmaxf(m4[2],v2); m4[3]=fmaxf(m4[3],v3);
            keepH[s*2]   = (unsigned int)f2h(v0) | ((unsigned int)f2h(v1) << 16);
            keepH[s*2+1] = (unsigned int)f2h(v2) | ((unsigned int)f2h(v3) << 16);
            __syncthreads();                       // full drain: staging visible, reads consumed
            cur ^= 1;
        }
        // ---- chunk scan: per-pixel running max across r-lanes, candidate pushes ----
        #pragma unroll
        for (int s2 = 1; s2 < 16; s2 <<= 1) {
            #pragma unroll
            for (int j = 0; j < 4; ++j) m4[j] = fmaxf(m4[j], __shfl_xor(m4[j], s2, 64));
        }
        float thr[4];
        #pragma unroll
        for (int j = 0; j < 4; ++j) thr[j] = m4[j] - MARGIN;
        #pragma unroll
        for (int s = 0; s < 8; ++s) {
            int nn = ((tc * 8 + s) << 4) + r;
            #pragma unroll
            for (int j2 = 0; j2 < 2; ++j2) {
                unsigned int pk = keepH[s * 2 + j2];
                float lo = h2f((unsigned short)(pk & 0xFFFFu));
                float hi = h2f((unsigned short)(pk >> 16));
                if (lo >= thr[j2 * 2]) {
                    int pos = atomicAdd(&candcount[w], 1);
                    if (pos < 256) candlist[w][pos] =
                        (unsigned int)nn | ((unsigned int)(w * 16 + g * 4 + j2 * 2) << 10);
                }
                if (hi >= thr[j2 * 2 + 1]) {
                    int pos = atomicAdd(&candcount[w], 1);
                    if (pos < 256) candlist[w][pos] =
                        (unsigned int)nn | ((unsigned int)(w * 16 + g * 4 + j2 * 2 + 1) << 10);
                }
            }
        }
    }

    // ---- exact fp32 refine: 4 candidates/wave in parallel, x from xT (L2-hot) ----
    int cc = candcount[w]; if (cc > 256) cc = 256;
    int sl = lane & 15, cg = lane >> 4;
    for (int t0 = 0; t0 < cc; t0 += 4) {
        int c = t0 + cg;
        bool valid = c < cc;
        unsigned int e = candlist[w][valid ? c : 0];
        int n = (int)(e & 1023u), pl = (int)(e >> 10);
        const float* xr = xT + (size_t)(p0 + pl) * C;
        const float* cenr = centers + (size_t)n * C;
        float s = 0.f;
        #pragma unroll
        for (int m = 0; m < 8; ++m) {
            int G = sl + (m << 4);
            float4 xv = *(const float4*)(xr + (G << 2));
            float4 cv = *(const float4*)(cenr + (G << 2));
            s = fmaf(xv.x, cv.x, s); s = fmaf(xv.y, cv.y, s);
            s = fmaf(xv.z, cv.z, s); s = fmaf(xv.w, cv.w, s);
        }
        #pragma unroll
        for (int s2 = 1; s2 < 16; s2 <<= 1) s += __shfl_xor(s, s2, 64);
        if (valid && sl == 0) {
            float val = s + gumbel[((size_t)b * N + n) * HW + hw0 + pl];
            unsigned long long key = ((unsigned long long)mono(val) << 32) | (unsigned int)(1023 - n);
            atomicMax(&pixkey[pl], key);
        }
    }
    __syncthreads();
    if (tid < 64) idxb[p0 + tid] = 1023 - (int)(unsigned int)(pixkey[tid] & 0xFFFFFFFFull);
}

// ---------- K6: preds (as float) + per-block loss partial sums ----------
__global__ __launch_bounds__(256) void k_preds(const int* __restrict__ idxb,
                                               const float* __restrict__ rowmax,
                                               const int* __restrict__ rowarg,
                                               float* __restrict__ preds_out,
                                               float* __restrict__ partial) {
    __shared__ float sv[256];
    int gid = blockIdx.x * 256 + threadIdx.x;
    int i = idxb[gid];
    preds_out[gid] = (float)rowarg[i];
    sv[threadIdx.x] = rowmax[i];
    __syncthreads();
    for (int s = 128; s > 0; s >>= 1) {
        if (threadIdx.x < s) sv[threadIdx.x] += sv[threadIdx.x + s];
        __syncthreads();
    }
    if (threadIdx.x == 0) partial[blockIdx.x] = sv[0];
}

// ---------- K7: gather rows of src by idx and write transposed (coalesced) ----------
__global__ __launch_bounds__(256) void k_gather(const float* __restrict__ src, int ncols,
                                                const int* __restrict__ idx,
                                                float* __restrict__ dst) {
    __shared__ float rows[64][65];
    int tile = blockIdx.x;
    int col0 = blockIdx.y * 64;
    int tid = threadIdx.x;
    int lane = tid & 63, w = tid >> 6;
    int b = tile >> 6, hw0 = (tile & 63) << 6;
    #pragma unroll
    for (int r8 = 0; r8 < 16; ++r8) {
        int r = w * 16 + r8;
        int row = idx[tile * 64 + r];
        rows[r][lane] = src[(size_t)row * ncols + col0 + lane];
    }
    __syncthreads();
    #pragma unroll
    for (int jj = 0; jj < 16; ++jj) {
        int j = col0 + w * 16 + jj;
        dst[((size_t)b * ncols + j) * HW + hw0 + lane] = rows[lane][w * 16 + jj];
    }
}

// ---------- K8: finalize loss ----------
__global__ __launch_bounds__(128) void k_loss(const float* __restrict__ partial,
                                              float* __restrict__ out) {
    __shared__ float sv[128];
    sv[threadIdx.x] = partial[threadIdx.x];
    __syncthreads();
    for (int s = 64; s > 0; s >>= 1) {
        if (threadIdx.x < s) sv[threadIdx.x] += sv[threadIdx.x + s];
        __syncthreads();
    }
    if (threadIdx.x == 0) out[0] = -(sv[0] / 32768.0f);
}

extern "C" void kernel_launch(void* const* d_in, const int* in_sizes, int n_in,
                              void* d_out, int out_size, void* d_ws, size_t ws_size,
                              hipStream_t stream) {
    const float* x        = (const float*)d_in[0];
    const float* centers  = (const float*)d_in[1];
    const float* clusters = (const float*)d_in[2];
    const float* gumbel   = (const float*)d_in[3];
    float* out = (float*)d_out;

    char* w = (char*)d_ws;
    int*   idxb    = (int*)w;                                  // 128 KB
    float* cnorm   = (float*)(w + 131072);                     // 4 KB
    float* clnorm  = cnorm + 1024;
    float* rowmax  = clnorm + 1024;
    int*   rowarg  = (int*)(rowmax + 1024);
    float* partial = (float*)(rowarg + 1024);
    float* M       = (float*)(w + 262144);                     // 4 MB
    unsigned short* cenB = (unsigned short*)(w + 4456448);     // 1 MB

    float* out_loss  = out;
    float* out_preds = out + 1;
    float* out_ip    = out + 1 + 32768;
    float* out_zq    = out + 1 + 32768 + (size_t)N * NPIX;

    // xT scratch lives in the zq output region (dead until the final gather)
    float* xT = out_zq;                                        // 32768 x 512 fp32, exact fit

    k_norms  <<<2048, 64, 0, stream>>>(centers, clusters, cnorm, clnorm);
    k_gemmM  <<<dim3(16, 16), 256, 0, stream>>>(centers, clusters, cnorm, clnorm, M);
    k_rowstat<<<1024, 256, 0, stream>>>(M, rowmax, rowarg);
    k_cenfrag<<<1024, 64, 0, stream>>>(centers, cenB);
    k_prepT  <<<4096, 256, 0, stream>>>(x, xT);
    k_fused  <<<512, 256, 0, stream>>>(xT, cenB, gumbel, centers, idxb);
    k_preds  <<<128, 256, 0, stream>>>(idxb, rowmax, rowarg, out_preds, partial);
    k_gather <<<dim3(512, 16), 256, 0, stream>>>(M, N, idxb, out_ip);
    k_gather <<<dim3(512, 8),  256, 0, stream>>>(centers, C, idxb, out_zq);
    k_loss   <<<1, 128, 0, stream>>>(partial, out_loss);
}

// Round 13
// 257.511 us; speedup vs baseline: 1.3298x; 1.1586x over previous
//
#include <hip/hip_runtime.h>
#include <math.h>

#define C 512
#define HW 4096
#define N 1024
#define NPIX 32768
#define MARGIN 2.0f

typedef short s16x8 __attribute__((ext_vector_type(8)));
typedef float f32x4 __attribute__((ext_vector_type(4)));

__device__ inline unsigned short f2bf(float f) {
    unsigned int u = __float_as_uint(f);
    return (unsigned short)((u + 0x7FFFu + ((u >> 16) & 1u)) >> 16);
}
__device__ inline float h2f(unsigned short u) {
    _Float16 h; __builtin_memcpy(&h, &u, 2); return (float)h;
}
__device__ inline unsigned short f2h(float f) {
    _Float16 h = (_Float16)f; unsigned short u; __builtin_memcpy(&u, &h, 2); return u;
}
__device__ inline unsigned int mono(float v) {
    unsigned int u = __float_as_uint(v);
    return (u & 0x80000000u) ? ~u : (u | 0x80000000u);
}
__device__ inline void gload_lds16(const void* gsrc, void* ldst) {
    __builtin_amdgcn_global_load_lds(
        (const __attribute__((address_space(1))) unsigned int*)gsrc,
        (__attribute__((address_space(3))) unsigned int*)ldst, 16, 0, 0);
}

// ---------- K0: row norms of centers (->cnorm) and clusters (->clnorm) ----------
__global__ __launch_bounds__(64) void k_norms(const float* __restrict__ centers,
                                              const float* __restrict__ clusters,
                                              float* __restrict__ cnorm,
                                              float* __restrict__ clnorm) {
    int r = blockIdx.x;
    const float* src = (r < N) ? (centers + (size_t)r * C) : (clusters + (size_t)(r - N) * C);
    int lane = threadIdx.x;
    float s = 0.f;
    for (int k = lane; k < C; k += 64) { float v = src[k]; s += v * v; }
    #pragma unroll
    for (int m = 1; m < 64; m <<= 1) s += __shfl_xor(s, m, 64);
    if (lane == 0) {
        float nrm = sqrtf(s);
        if (nrm < 1e-12f) nrm = 1e-12f;
        if (r < N) cnorm[r] = nrm; else clnorm[r - N] = nrm;
    }
}

// ---------- K1: M[i][j] = dot(centers[i],clusters[j]) / (cnorm[i]*clnorm[j]) ----------
__global__ __launch_bounds__(256) void k_gemmM(const float* __restrict__ centers,
                                               const float* __restrict__ clusters,
                                               const float* __restrict__ cnorm,
                                               const float* __restrict__ clnorm,
                                               float* __restrict__ M) {
    __shared__ float as[32][68];
    __shared__ float bs[32][68];
    int tid = threadIdx.x;
    int tx = tid & 15, ty = tid >> 4;
    int i0 = blockIdx.x * 64, j0 = blockIdx.y * 64;
    int lrow = tid >> 2, lkq = (tid & 3) * 8;
    float acc[4][4] = {};
    for (int kc = 0; kc < C; kc += 32) {
        float4 a0 = *(const float4*)(centers + (size_t)(i0 + lrow) * C + kc + lkq);
        float4 a1 = *(const float4*)(centers + (size_t)(i0 + lrow) * C + kc + lkq + 4);
        float4 b0 = *(const float4*)(clusters + (size_t)(j0 + lrow) * C + kc + lkq);
        float4 b1 = *(const float4*)(clusters + (size_t)(j0 + lrow) * C + kc + lkq + 4);
        __syncthreads();
        as[lkq+0][lrow]=a0.x; as[lkq+1][lrow]=a0.y; as[lkq+2][lrow]=a0.z; as[lkq+3][lrow]=a0.w;
        as[lkq+4][lrow]=a1.x; as[lkq+5][lrow]=a1.y; as[lkq+6][lrow]=a1.z; as[lkq+7][lrow]=a1.w;
        bs[lkq+0][lrow]=b0.x; bs[lkq+1][lrow]=b0.y; bs[lkq+2][lrow]=b0.z; bs[lkq+3][lrow]=b0.w;
        bs[lkq+4][lrow]=b1.x; bs[lkq+5][lrow]=b1.y; bs[lkq+6][lrow]=b1.z; bs[lkq+7][lrow]=b1.w;
        __syncthreads();
        #pragma unroll
        for (int k = 0; k < 32; k += 4) {
            float av[4][4], bv[4][4];
            #pragma unroll
            for (int kk = 0; kk < 4; ++kk) {
                float4 ta = *(const float4*)&as[k+kk][tx*4];
                float4 tb = *(const float4*)&bs[k+kk][ty*4];
                av[kk][0]=ta.x; av[kk][1]=ta.y; av[kk][2]=ta.z; av[kk][3]=ta.w;
                bv[kk][0]=tb.x; bv[kk][1]=tb.y; bv[kk][2]=tb.z; bv[kk][3]=tb.w;
            }
            #pragma unroll
            for (int kk = 0; kk < 4; ++kk)
                #pragma unroll
                for (int ii = 0; ii < 4; ++ii)
                    #pragma unroll
                    for (int jj = 0; jj < 4; ++jj)
                        acc[ii][jj] = fmaf(av[kk][ii], bv[kk][jj], acc[ii][jj]);
        }
    }
    float rci[4], rcj[4];
    #pragma unroll
    for (int ii = 0; ii < 4; ++ii) rci[ii] = cnorm[i0 + tx*4 + ii];
    #pragma unroll
    for (int jj = 0; jj < 4; ++jj) rcj[jj] = clnorm[j0 + ty*4 + jj];
    #pragma unroll
    for (int ii = 0; ii < 4; ++ii)
        #pragma unroll
        for (int jj = 0; jj < 4; ++jj)
            M[(size_t)(i0 + tx*4 + ii) * N + (j0 + ty*4 + jj)] = acc[ii][jj] / (rci[ii] * rcj[jj]);
}

// ---------- K2: per-row max + argmax (first-index tie-break) of M ----------
__global__ __launch_bounds__(256) void k_rowstat(const float* __restrict__ M,
                                                 float* __restrict__ rowmax,
                                                 int* __restrict__ rowarg) {
    __shared__ float sv[256];
    __shared__ int   sa[256];
    int i = blockIdx.x, tid = threadIdx.x;
    float bv = -INFINITY; int ba = 0;
    for (int j = tid; j < N; j += 256) {
        float v = M[(size_t)i * N + j];
        if (v > bv || (v == bv && j < ba)) { bv = v; ba = j; }
    }
    sv[tid] = bv; sa[tid] = ba;
    __syncthreads();
    for (int s = 128; s > 0; s >>= 1) {
        if (tid < s) {
            float v = sv[tid + s]; int a = sa[tid + s];
            if (v > sv[tid] || (v == sv[tid] && a < sa[tid])) { sv[tid] = v; sa[tid] = a; }
        }
        __syncthreads();
    }
    if (tid == 0) { rowmax[i] = sv[0]; rowarg[i] = sa[0]; }
}

// ---------- K3: transpose x[b][k][p] -> xT[b*4096+p][k] (fp32) ----------
__global__ __launch_bounds__(256) void k_prepT(const float* __restrict__ x,
                                               float* __restrict__ xT) {
    __shared__ float t[64][65];
    int bidx = blockIdx.x;              // 8 b * 8 ktile * 64 ptile
    int pt = bidx & 63, kt = (bidx >> 6) & 7, b = bidx >> 9;
    int r = threadIdx.x >> 4, c4 = (threadIdx.x & 15) * 4;
    const float* src = x + ((size_t)b * C + kt * 64) * HW + pt * 64;
    #pragma unroll
    for (int rr = 0; rr < 4; ++rr) {
        int row = rr * 16 + r;
        float4 v = *(const float4*)(src + (size_t)row * HW + c4);
        t[row][c4] = v.x; t[row][c4+1] = v.y; t[row][c4+2] = v.z; t[row][c4+3] = v.w;
    }
    __syncthreads();
    float* dst = xT + ((size_t)b * HW + pt * 64) * C + kt * 64;
    #pragma unroll
    for (int rr = 0; rr < 4; ++rr) {
        int row = rr * 16 + r;          // pixel within tile
        float4 v = { t[c4][row], t[c4+1][row], t[c4+2][row], t[c4+3][row] };
        *(float4*)(dst + (size_t)row * C + c4) = v;
    }
}

// ---------- K4: centers -> bf16 MFMA B-fragments (fragment-linear) ----------
__global__ __launch_bounds__(64) void k_cenfrag(const float* __restrict__ centers,
                                                unsigned short* __restrict__ cenB) {
    int f = blockIdx.x;                 // nt*16 + kt
    int nt = f >> 4, kt = f & 15;
    int lane = threadIdx.x;
    int r = lane & 15, g = lane >> 4;
    const float* src = centers + (size_t)(nt * 16 + r) * C + kt * 32 + g * 4;
    float4 lo = *(const float4*)src;
    float4 hi = *(const float4*)(src + 16);
    union { unsigned short us[8]; uint4 q; } u;
    u.us[0]=f2bf(lo.x); u.us[1]=f2bf(lo.y); u.us[2]=f2bf(lo.z); u.us[3]=f2bf(lo.w);
    u.us[4]=f2bf(hi.x); u.us[5]=f2bf(hi.y); u.us[6]=f2bf(hi.z); u.us[7]=f2bf(hi.w);
    *(uint4*)(cenB + ((size_t)f * 64 + lane) * 8) = u.q;
}

// ---------- K5: FUSED — 512 blocks x 64 px, 3-buffer counted-vmcnt pipeline ----------
__global__ __launch_bounds__(256, 2) void k_fused(const float* __restrict__ xT,
                                                  const unsigned short* __restrict__ cenB,
                                                  const float* __restrict__ gumbel,
                                                  const float* __restrict__ centers,
                                                  int* __restrict__ idxb) {
    __shared__ unsigned short cen[3][8192];        // 3 x 16 KB cen tile rotation
    __shared__ float glds[3][1024];                // 3 x 4 KB gumbel tile (XOR-swz granules)
    __shared__ unsigned long long pixkey[64];
    __shared__ unsigned int candlist[4][256];
    __shared__ int candcount[4];

    int tid = threadIdx.x;
    int lane = tid & 63, w = tid >> 6;             // 4 waves; wave = px-tile
    int r = lane & 15, g = lane >> 4;

    int p0 = blockIdx.x * 64;
    int b = p0 >> 12, hw0 = p0 & (HW - 1);

    if (tid < 64) pixkey[tid] = 0ull;
    if (tid < 4) candcount[tid] = 0;

    // ---- A fragments FIRST (fully consumed -> vmcnt clean before stage issues) ----
    s16x8 a[16];
    {
        const float* xrow = xT + (size_t)(p0 + w * 16 + r) * C;
        #pragma unroll
        for (int kt = 0; kt < 16; ++kt) {
            float4 lo = *(const float4*)(xrow + kt * 32 + g * 4);
            float4 hi = *(const float4*)(xrow + kt * 32 + 16 + g * 4);
            s16x8 t;
            t[0]=(short)f2bf(lo.x); t[1]=(short)f2bf(lo.y); t[2]=(short)f2bf(lo.z); t[3]=(short)f2bf(lo.w);
            t[4]=(short)f2bf(hi.x); t[5]=(short)f2bf(hi.y); t[6]=(short)f2bf(hi.z); t[7]=(short)f2bf(hi.w);
            a[kt] = t;
        }
    }

    // gumbel staging: thread tid stages 16B of row (tid>>4), px-granule ((tid^(tid>>4))&15)
    int grow_ = tid >> 4;
    int gcol_ = ((tid ^ (tid >> 4)) & 15) * 4;
    const float* gbase = gumbel + (size_t)b * N * HW + hw0 + gcol_;

    // STAGE(T,BUF): exactly 5 VMEM ops (4 cen + 1 gumbel), all global_load_lds
    #define STAGE(T, BUF) { \
        const char* s_ = (const char*)cenB + (size_t)(T) * 16384 + w * 4096 + lane * 16; \
        char* d_ = (char*)&cen[0][0] + (BUF) * 16384 + w * 4096; \
        gload_lds16(s_, d_); gload_lds16(s_ + 1024, d_ + 1024); \
        gload_lds16(s_ + 2048, d_ + 2048); gload_lds16(s_ + 3072, d_ + 3072); \
        gload_lds16(gbase + (size_t)((T) * 16 + grow_) * HW, \
                    (char*)&glds[0][0] + (BUF) * 4096 + tid * 16); \
    }

    __builtin_amdgcn_sched_barrier(0);
    STAGE(0, 0);
    STAGE(1, 1);
    __builtin_amdgcn_sched_barrier(0);
    asm volatile("s_waitcnt vmcnt(5)" ::: "memory");   // stage(0) complete
    __builtin_amdgcn_s_barrier();
    __builtin_amdgcn_sched_barrier(0);

    float m4[4] = {-INFINITY, -INFINITY, -INFINITY, -INFINITY};
    int c0 = 0;                                     // buffer holding tile t
    int gswz = r * 64 + ((((w << 2) + g) ^ r) << 2);

    for (int tc = 0; tc < 8; ++tc) {                // 8 chunks x 8 tiles = 64 n-tiles
        unsigned int keepH[16];
        #pragma unroll
        for (int s = 0; s < 8; ++s) {
            int t = tc * 8 + s;
            // ---- MFMA phase on buf c0 ----
            const s16x8* bp = (const s16x8*)((char*)&cen[0][0] + c0 * 16384) + lane;
            f32x4 acc0 = {0.f,0.f,0.f,0.f}, acc1 = {0.f,0.f,0.f,0.f};
            #pragma unroll
            for (int kt = 0; kt < 16; kt += 2) {
                acc0 = __builtin_amdgcn_mfma_f32_16x16x32_bf16(a[kt],   bp[kt*64],     acc0, 0,0,0);
                acc1 = __builtin_amdgcn_mfma_f32_16x16x32_bf16(a[kt+1], bp[(kt+1)*64], acc1, 0,0,0);
            }
            f32x4 gv = *(const f32x4*)((const float*)&glds[0][0] + c0 * 1024 + gswz);
            float v0 = acc0[0]+acc1[0]+gv[0], v1 = acc0[1]+acc1[1]+gv[1];
            float v2 = acc0[2]+acc1[2]+gv[2], v3 = acc0[3]+acc1[3]+gv[3];
            m4[0]=fmaxf(m4[0],v0); m4[1]=fmaxf(m4[1],v1);
            m4[2]=fmaxf(m4[2],v2); m4[3]=fmaxf(m4[3],v3);
            keepH[s*2]   = (unsigned int)f2h(v0) | ((unsigned int)f2h(v1) << 16);
            keepH[s*2+1] = (unsigned int)f2h(v2) | ((unsigned int)f2h(v3) << 16);
            // ---- B1: all waves done READING buf c0 (ds_reads drained) ----
            asm volatile("s_waitcnt lgkmcnt(0)" ::: "memory");
            __builtin_amdgcn_sched_barrier(0);
            __builtin_amdgcn_s_barrier();
            __builtin_amdgcn_sched_barrier(0);
            // ---- issue stage(t+2) into buf (c0+2)%3 (its readers finished at B1 of iter t-1) ----
            int c2 = c0 + 2; if (c2 >= 3) c2 -= 3;
            if (t + 2 <= 63) { STAGE(t + 2, c2); }
            __builtin_amdgcn_sched_barrier(0);
            // ---- wait stage(t+1) only; stage(t+2) stays in flight ----
            if (t + 2 <= 63)      { asm volatile("s_waitcnt vmcnt(5)" ::: "memory"); }
            else if (t + 1 <= 63) { asm volatile("s_waitcnt vmcnt(0)" ::: "memory"); }
            __builtin_amdgcn_s_barrier();           // B2: buf (c0+1)%3 ready for all
            __builtin_amdgcn_sched_barrier(0);
            c0 = c0 + 1; if (c0 >= 3) c0 -= 3;
        }
        // ---- chunk scan: per-pixel running max across r-lanes, candidate pushes ----
        #pragma unroll
        for (int s2 = 1; s2 < 16; s2 <<= 1) {
            #pragma unroll
            for (int j = 0; j < 4; ++j) m4[j] = fmaxf(m4[j], __shfl_xor(m4[j], s2, 64));
        }
        float thr[4];
        #pragma unroll
        for (int j = 0; j < 4; ++j) thr[j] = m4[j] - MARGIN;
        #pragma unroll
        for (int s = 0; s < 8; ++s) {
            int nn = ((tc * 8 + s) << 4) + r;
            #pragma unroll
            for (int j2 = 0; j2 < 2; ++j2) {
                unsigned int pk = keepH[s * 2 + j2];
                float lo = h2f((unsigned short)(pk & 0xFFFFu));
                float hi = h2f((unsigned short)(pk >> 16));
                if (lo >= thr[j2 * 2]) {
                    int pos = atomicAdd(&candcount[w], 1);
                    if (pos < 256) candlist[w][pos] =
                        (unsigned int)nn | ((unsigned int)(w * 16 + g * 4 + j2 * 2) << 10);
                }
                if (hi >= thr[j2 * 2 + 1]) {
                    int pos = atomicAdd(&candcount[w], 1);
                    if (pos < 256) candlist[w][pos] =
                        (unsigned int)nn | ((unsigned int)(w * 16 + g * 4 + j2 * 2 + 1) << 10);
                }
            }
        }
    }
    #undef STAGE

    // ---- exact fp32 refine: 4 candidates/wave in parallel, x from xT (L2-hot) ----
    int cc = candcount[w]; if (cc > 256) cc = 256;
    int sl = lane & 15, cg = lane >> 4;
    for (int t0 = 0; t0 < cc; t0 += 4) {
        int c = t0 + cg;
        bool valid = c < cc;
        unsigned int e = candlist[w][valid ? c : 0];
        int n = (int)(e & 1023u), pl = (int)(e >> 10);
        const float* xr = xT + (size_t)(p0 + pl) * C;
        const float* cenr = centers + (size_t)n * C;
        float s = 0.f;
        #pragma unroll
        for (int m = 0; m < 8; ++m) {
            int G = sl + (m << 4);
            float4 xv = *(const float4*)(xr + (G << 2));
            float4 cv = *(const float4*)(cenr + (G << 2));
            s = fmaf(xv.x, cv.x, s); s = fmaf(xv.y, cv.y, s);
            s = fmaf(xv.z, cv.z, s); s = fmaf(xv.w, cv.w, s);
        }
        #pragma unroll
        for (int s2 = 1; s2 < 16; s2 <<= 1) s += __shfl_xor(s, s2, 64);
        if (valid && sl == 0) {
            float val = s + gumbel[((size_t)b * N + n) * HW + hw0 + pl];
            unsigned long long key = ((unsigned long long)mono(val) << 32) | (unsigned int)(1023 - n);
            atomicMax(&pixkey[pl], key);
        }
    }
    __syncthreads();
    if (tid < 64) idxb[p0 + tid] = 1023 - (int)(unsigned int)(pixkey[tid] & 0xFFFFFFFFull);
}

// ---------- K6: preds (as float) + per-block loss partial sums ----------
__global__ __launch_bounds__(256) void k_preds(const int* __restrict__ idxb,
                                               const float* __restrict__ rowmax,
                                               const int* __restrict__ rowarg,
                                               float* __restrict__ preds_out,
                                               float* __restrict__ partial) {
    __shared__ float sv[256];
    int gid = blockIdx.x * 256 + threadIdx.x;
    int i = idxb[gid];
    preds_out[gid] = (float)rowarg[i];
    sv[threadIdx.x] = rowmax[i];
    __syncthreads();
    for (int s = 128; s > 0; s >>= 1) {
        if (threadIdx.x < s) sv[threadIdx.x] += sv[threadIdx.x + s];
        __syncthreads();
    }
    if (threadIdx.x == 0) partial[blockIdx.x] = sv[0];
}

// ---------- K7: gather rows of src by idx and write transposed (coalesced) ----------
__global__ __launch_bounds__(256) void k_gather(const float* __restrict__ src, int ncols,
                                                const int* __restrict__ idx,
                                                float* __restrict__ dst) {
    __shared__ float rows[64][65];
    int tile = blockIdx.x;
    int col0 = blockIdx.y * 64;
    int tid = threadIdx.x;
    int lane = tid & 63, w = tid >> 6;
    int b = tile >> 6, hw0 = (tile & 63) << 6;
    #pragma unroll
    for (int r8 = 0; r8 < 16; ++r8) {
        int r = w * 16 + r8;
        int row = idx[tile * 64 + r];
        rows[r][lane] = src[(size_t)row * ncols + col0 + lane];
    }
    __syncthreads();
    #pragma unroll
    for (int jj = 0; jj < 16; ++jj) {
        int j = col0 + w * 16 + jj;
        dst[((size_t)b * ncols + j) * HW + hw0 + lane] = rows[lane][w * 16 + jj];
    }
}

// ---------- K8: finalize loss ----------
__global__ __launch_bounds__(128) void k_loss(const float* __restrict__ partial,
                                              float* __restrict__ out) {
    __shared__ float sv[128];
    sv[threadIdx.x] = partial[threadIdx.x];
    __syncthreads();
    for (int s = 64; s > 0; s >>= 1) {
        if (threadIdx.x < s) sv[threadIdx.x] += sv[threadIdx.x + s];
        __syncthreads();
    }
    if (threadIdx.x == 0) out[0] = -(sv[0] / 32768.0f);
}

extern "C" void kernel_launch(void* const* d_in, const int* in_sizes, int n_in,
                              void* d_out, int out_size, void* d_ws, size_t ws_size,
                              hipStream_t stream) {
    const float* x        = (const float*)d_in[0];
    const float* centers  = (const float*)d_in[1];
    const float* clusters = (const float*)d_in[2];
    const float* gumbel   = (const float*)d_in[3];
    float* out = (float*)d_out;

    char* w = (char*)d_ws;
    int*   idxb    = (int*)w;                                  // 128 KB
    float* cnorm   = (float*)(w + 131072);                     // 4 KB
    float* clnorm  = cnorm + 1024;
    float* rowmax  = clnorm + 1024;
    int*   rowarg  = (int*)(rowmax + 1024);
    float* partial = (float*)(rowarg + 1024);
    float* M       = (float*)(w + 262144);                     // 4 MB
    unsigned short* cenB = (unsigned short*)(w + 4456448);     // 1 MB

    float* out_loss  = out;
    float* out_preds = out + 1;
    float* out_ip    = out + 1 + 32768;
    float* out_zq    = out + 1 + 32768 + (size_t)N * NPIX;

    // xT scratch lives in the zq output region (dead until the final gather)
    float* xT = out_zq;                                        // 32768 x 512 fp32, exact fit

    k_norms  <<<2048, 64, 0, stream>>>(centers, clusters, cnorm, clnorm);
    k_gemmM  <<<dim3(16, 16), 256, 0, stream>>>(centers, clusters, cnorm, clnorm, M);
    k_rowstat<<<1024, 256, 0, stream>>>(M, rowmax, rowarg);
    k_cenfrag<<<1024, 64, 0, stream>>>(centers, cenB);
    k_prepT  <<<4096, 256, 0, stream>>>(x, xT);
    k_fused  <<<512, 256, 0, stream>>>(xT, cenB, gumbel, centers, idxb);
    k_preds  <<<128, 256, 0, stream>>>(idxb, rowmax, rowarg, out_preds, partial);
    k_gather <<<dim3(512, 16), 256, 0, stream>>>(M, N, idxb, out_ip);
    k_gather <<<dim3(512, 8),  256, 0, stream>>>(centers, C, idxb, out_zq);
    k_loss   <<<1, 128, 0, stream>>>(partial, out_loss);
}